// Round 16
// baseline (226.951 us; speedup 1.0000x reference)
//
#include <hip/hip_runtime.h>
#include <hip/hip_bf16.h>

#define NN 100000
#define EE 1600000
#define IN_DIM 512
#define HID 64
#define NB1 391          // 256-node buckets: 391*256 = 100096 >= NN
#define NCH 196          // chunks
#define CHUNK 8192       // 196*8192 >= EE
#define NGEMM 1563       // (NN+63)/64
#define ARENA 5120       // per-bucket edge arena (expect ~4092, ~16-sigma margin)
#define GA 800           // gemm tiles in scatter launch
#define GB (NGEMM - GA)  // gemm tiles in sort launch

typedef __attribute__((ext_vector_type(8))) short bf16x8;
typedef __attribute__((ext_vector_type(4))) float f32x4;

static __device__ __forceinline__ short f2bf(float f) {
    __hip_bfloat16 h = __float2bfloat16(f);
    return *reinterpret_cast<short*>(&h);
}
static __device__ __forceinline__ float bf2f(unsigned short u) {
    union { unsigned int i; float f; } c; c.i = ((unsigned int)u) << 16;
    return c.f;
}

// ---- K0: zero the degree accumulator (rocclr small-fill kernel is ~118us) ----
__global__ __launch_bounds__(256) void zero_deg_kernel(int4* __restrict__ deg4) {
    int i = blockIdx.x * 256 + threadIdx.x;
    if (i < NN / 4) deg4[i] = make_int4(0, 0, 0, 0);   // NN % 4 == 0
}

// ---- shared device body: MFMA GEMM1 tile; stores y = bf16(xt1) (UNscaled) ----
__device__ __forceinline__ void do_gemm(int gb, const float* __restrict__ x,
                                        const bf16x8* __restrict__ W1p,
                                        const int* __restrict__ deg,
                                        float* __restrict__ dis,
                                        unsigned short* __restrict__ y) {
    const int wave = threadIdx.x >> 6;
    const int lane = threadIdx.x & 63;
    const int r = lane & 15;        // A row within wave tile / B,C col
    const int kg = lane >> 4;       // k-group
    const int row0 = gb * 64 + wave * 16;
    const int rowc = min(row0 + r, NN - 1);
    const float* xr = x + (size_t)rowc * IN_DIM;

    f32x4 acc[4] = {};
#pragma unroll
    for (int ks = 0; ks < 16; ++ks) {
        const int k0 = ks * 32 + kg * 8;
        float4 xa = *(const float4*)(xr + k0);
        float4 xb = *(const float4*)(xr + k0 + 4);
        bf16x8 a;
        a[0] = f2bf(xa.x); a[1] = f2bf(xa.y); a[2] = f2bf(xa.z); a[3] = f2bf(xa.w);
        a[4] = f2bf(xb.x); a[5] = f2bf(xb.y); a[6] = f2bf(xb.z); a[7] = f2bf(xb.w);
        const int bbase = (ks * 4 + kg) * 64;
#pragma unroll
        for (int cb = 0; cb < 4; ++cb) {
            bf16x8 bfr = W1p[bbase + cb * 16 + r];
            acc[cb] = __builtin_amdgcn_mfma_f32_16x16x32_bf16(a, bfr, acc[cb], 0, 0, 0);
        }
    }
    // per-row dis = rsqrt(deg+1) published; y = bf16(xt1) (precision: R12 path)
    // C/D: col = lane&15 (=r), row = kg*4 + reg
#pragma unroll
    for (int reg = 0; reg < 4; ++reg) {
        int ro = row0 + kg * 4 + reg;
        if (r == 0 && ro < NN) dis[ro] = rsqrtf((float)deg[ro] + 1.0f);
    }
#pragma unroll
    for (int cb = 0; cb < 4; ++cb) {
#pragma unroll
        for (int reg = 0; reg < 4; ++reg) {
            int ro = row0 + kg * 4 + reg;
            if (ro < NN) y[(size_t)ro * HID + cb * 16 + r] =
                (unsigned short)f2bf(acc[cb][reg]);
        }
    }
}

// ---- K1: W1 pack (blocks 0..15) + per-chunk histogram + global degree --------
__global__ __launch_bounds__(256) void pack_hist_kernel(const float* __restrict__ W1,
                                                        bf16x8* __restrict__ W1p,
                                                        const int* __restrict__ dst,
                                                        int* __restrict__ cnt2d,
                                                        int* __restrict__ deg) {
    if (blockIdx.x < 16) {
        int t = blockIdx.x * 256 + threadIdx.x;   // 0..4095
        int kstep = t >> 8;
        int kb = (t >> 6) & 3;
        int col = t & 63;
        int kbase = kstep * 32 + kb * 8;
        bf16x8 v;
#pragma unroll
        for (int j = 0; j < 8; ++j) v[j] = f2bf(W1[(size_t)(kbase + j) * HID + col]);
        W1p[t] = v;
    } else {
        __shared__ int h[NB1];
        const int c = blockIdx.x - 16;
        const int t = threadIdx.x;
        for (int i = t; i < NB1; i += 256) h[i] = 0;
        __syncthreads();
        const int base = c * CHUNK;
        for (int i = t; i < CHUNK; i += 256) {
            int e = base + i;
            if (e < EE) {
                int d = dst[e];
                atomicAdd(&h[d >> 8], 1);
                atomicAdd(&deg[d], 1);
            }
        }
        __syncthreads();
        for (int i = t; i < NB1; i += 256) cnt2d[c * NB1 + i] = h[i];
    }
}

// ---- K2: arena scatter w/ redundant chunk-prefix (blocks 0..NCH-1)
//          + gemm tiles [0,GA) (rest) -----------------------------------------
__global__ __launch_bounds__(256) void scatter_gemm_kernel(
        const int* __restrict__ src, const int* __restrict__ dst,
        const int* __restrict__ cnt2d, unsigned int* __restrict__ pairs,
        int* __restrict__ edge_cnt,
        const float* __restrict__ x, const bf16x8* __restrict__ W1p,
        const int* __restrict__ deg, float* __restrict__ dis,
        unsigned short* __restrict__ y) {
    if (blockIdx.x < NCH) {
        __shared__ int cur[NB1];
        const int c = blockIdx.x;
        const int t = threadIdx.x;
        for (int i = t; i < NB1; i += 256) {
            int run = 0, pp = 0;
            for (int c2 = 0; c2 < NCH; ++c2) {
                int v = cnt2d[c2 * NB1 + i];
                if (c2 == c) pp = run;
                run += v;
            }
            cur[i] = i * ARENA + pp;
            if (c == 0) edge_cnt[i] = run;   // bucket totals (block 0 publishes)
        }
        __syncthreads();
        const int base = c * CHUNK;
        for (int i = t; i < CHUNK; i += 256) {
            int e = base + i;
            if (e < EE) {
                int s = src[e], d = dst[e];
                int bkt = d >> 8;
                int pos = atomicAdd(&cur[bkt], 1);
                if (pos < (bkt + 1) * ARENA)   // safety clamp
                    pairs[pos] = ((unsigned int)s << 8) | (unsigned int)(d & 255);
            }
        }
    } else {
        do_gemm(blockIdx.x - NCH, x, W1p, deg, dis, y);
    }
}

// ---- K3: per-bucket CSR sort (blocks 0..NB1-1) + gemm tiles [GA,NGEMM) -------
__global__ __launch_bounds__(256) void sort_gemm_kernel(
        const unsigned int* __restrict__ pairs, const int* __restrict__ edge_cnt,
        int* __restrict__ offsets, int* __restrict__ cursor,
        int* __restrict__ sorted_src,
        const float* __restrict__ x, const bf16x8* __restrict__ W1p,
        const int* __restrict__ deg, float* __restrict__ dis,
        unsigned short* __restrict__ y) {
    if (blockIdx.x < NB1) {
        __shared__ int sdeg[256];
        __shared__ int sinc[256];
        __shared__ int scur[256];
        const int b = blockIdx.x;
        const int t = threadIdx.x;
        const int n0 = b << 8;
        const int nn = min(256, NN - n0);
        const int e0 = b * ARENA;
        const int e1 = e0 + min(edge_cnt[b], ARENA);

        sdeg[t] = 0;
        __syncthreads();
        for (int e = e0 + t; e < e1; e += 256)
            atomicAdd(&sdeg[pairs[e] & 255u], 1);
        __syncthreads();
        sinc[t] = sdeg[t];
        __syncthreads();
        for (int off = 1; off < 256; off <<= 1) {
            int v = (t >= off) ? sinc[t - off] : 0;
            __syncthreads();
            sinc[t] += v;
            __syncthreads();
        }
        int excl = sinc[t] - sdeg[t];
        scur[t] = excl;
        if (t < nn) {
            offsets[n0 + t] = e0 + excl;
            cursor[n0 + t]  = e0 + excl + sdeg[t];
        }
        __syncthreads();
        for (int e = e0 + t; e < e1; e += 256) {
            unsigned int p = pairs[e];
            int pos = atomicAdd(&scur[p & 255u], 1);
            sorted_src[e0 + pos] = (int)(p >> 8);
        }
    } else {
        do_gemm(GA + (blockIdx.x - NB1), x, W1p, deg, dis, y);
    }
}

// ---- K4: pull aggregation layer1 (wave/node, 8 edges in flight) + GEMM2 ------
// y unscaled bf16; per-edge fp32 dis[s] multiply (R12 precision path)
__global__ __launch_bounds__(256) void agg1_fused_kernel(
        const int* __restrict__ offsets, const int* __restrict__ cursor,
        const int* __restrict__ sorted_src, const unsigned short* __restrict__ y,
        const float* __restrict__ dis, const float* __restrict__ b1,
        const float* __restrict__ W2, float* __restrict__ z) {
    int node = blockIdx.x * 4 + (threadIdx.x >> 6);
    if (node >= NN) return;
    const int lane = threadIdx.x & 63;
    const int grp = lane >> 3;      // 8 edge groups
    const int fl = lane & 7;        // feature slice: feats fl*8 .. fl*8+7
    const int beg = offsets[node], end = cursor[node];
    const float dd = dis[node];
    float acc[8] = {};

    // self-loop (group 0 only; folded in by the cross-group reduce): xt1 * dd
    if (grp == 0) {
        bf16x8 v = *(const bf16x8*)(y + (size_t)node * HID + fl * 8);
#pragma unroll
        for (int k = 0; k < 8; ++k) acc[k] = bf2f((unsigned short)v[k]) * dd;
    }
    for (int base = beg; base < end; base += 64) {
        int m = min(64, end - base);
        int s = 0;
        float nd = 0.f;
        if (lane < m) {
            s = sorted_src[base + lane];   // coalesced batch load
            nd = dis[s];
        }
#pragma unroll 2
        for (int jj = 0; jj < m; jj += 8) {
            int j = jj + grp;
            if (j < m) {
                int sj = __shfl(s, j);
                float wj = __shfl(nd, j);
                bf16x8 v = *(const bf16x8*)(y + (size_t)sj * HID + fl * 8);
#pragma unroll
                for (int k = 0; k < 8; ++k) acc[k] += bf2f((unsigned short)v[k]) * wj;
            }
        }
    }
    // reduce across the 8 edge groups (lane bits 3,4,5)
#pragma unroll
    for (int k = 0; k < 8; ++k) {
        acc[k] += __shfl_xor(acc[k], 8);
        acc[k] += __shfl_xor(acc[k], 16);
        acc[k] += __shfl_xor(acc[k], 32);
    }
    // h = relu(dd*acc + b1); fused GEMM2 (feats f = fl*8+k)
    float4 b_lo = *(const float4*)(b1 + fl * 8);
    float4 b_hi = *(const float4*)(b1 + fl * 8 + 4);
    float4 w0 = *(const float4*)(W2 + fl * 16);        // rows fl*8+0,1
    float4 w1 = *(const float4*)(W2 + fl * 16 + 4);    // rows fl*8+2,3
    float4 w2 = *(const float4*)(W2 + fl * 16 + 8);    // rows fl*8+4,5
    float4 w3 = *(const float4*)(W2 + fl * 16 + 12);   // rows fl*8+6,7
    float h0 = fmaxf(dd * acc[0] + b_lo.x, 0.f);
    float h1 = fmaxf(dd * acc[1] + b_lo.y, 0.f);
    float h2 = fmaxf(dd * acc[2] + b_lo.z, 0.f);
    float h3 = fmaxf(dd * acc[3] + b_lo.w, 0.f);
    float h4 = fmaxf(dd * acc[4] + b_hi.x, 0.f);
    float h5 = fmaxf(dd * acc[5] + b_hi.y, 0.f);
    float h6 = fmaxf(dd * acc[6] + b_hi.z, 0.f);
    float h7 = fmaxf(dd * acc[7] + b_hi.w, 0.f);
    float a0 = h0 * w0.x + h1 * w0.z + h2 * w1.x + h3 * w1.z
             + h4 * w2.x + h5 * w2.z + h6 * w3.x + h7 * w3.z;
    float a1 = h0 * w0.y + h1 * w0.w + h2 * w1.y + h3 * w1.w
             + h4 * w2.y + h5 * w2.w + h6 * w3.y + h7 * w3.w;
    a0 += __shfl_xor(a0, 1); a0 += __shfl_xor(a0, 2); a0 += __shfl_xor(a0, 4);
    a1 += __shfl_xor(a1, 1); a1 += __shfl_xor(a1, 2); a1 += __shfl_xor(a1, 4);
    if (lane == 0) *(float2*)(z + (size_t)node * 2) = make_float2(dd * a0, dd * a1);
}

// ---- K5: layer2 aggregation over pre-scaled z (fp32 fold) + log_softmax ------
__global__ void agg2_final_kernel(const int* __restrict__ offsets, const int* __restrict__ cursor,
                                  const int* __restrict__ sorted_src,
                                  const float* __restrict__ dis,
                                  const float* __restrict__ z,
                                  const float* __restrict__ b2,
                                  float* __restrict__ out) {
    int node = blockIdx.x * 256 + threadIdx.x;
    if (node >= NN) return;
    int beg = offsets[node], end = cursor[node];
    float dd = dis[node];
    float2 zs = *(const float2*)(z + (size_t)node * 2);
    float a0 = zs.x, a1 = zs.y;     // self-loop (z pre-scaled by dis)
    for (int p = beg; p < end; ++p) {
        int s = sorted_src[p];
        float2 v = *(const float2*)(z + (size_t)s * 2);
        a0 += v.x;
        a1 += v.y;
    }
    float v0 = dd * a0 + b2[0], v1 = dd * a1 + b2[1];
    float m = fmaxf(v0, v1);
    float lse = m + logf(expf(v0 - m) + expf(v1 - m));
    out[(size_t)node * 2 + 0] = v0 - lse;
    out[(size_t)node * 2 + 1] = v1 - lse;
}

extern "C" void kernel_launch(void* const* d_in, const int* in_sizes, int n_in,
                              void* d_out, int out_size, void* d_ws, size_t ws_size,
                              hipStream_t stream) {
    const float* x  = (const float*)d_in[0];
    const int* ei   = (const int*)d_in[1];
    const float* W1 = (const float*)d_in[2];
    const float* b1 = (const float*)d_in[3];
    const float* W2 = (const float*)d_in[4];
    const float* b2 = (const float*)d_in[5];
    const int* src = ei;
    const int* dst = ei + EE;
    float* out = (float*)d_out;

    // workspace layout
    unsigned short* y = (unsigned short*)d_ws;                      // N*64 bf16 = 12.8 MB
    float* dis        = (float*)(y + (size_t)NN * HID);             // N
    int*   deg        = (int*)(dis + NN);                           // N
    int*   offsets    = deg + NN;                                   // N
    int*   cursor     = offsets + NN;                               // N
    float* z          = (float*)(cursor + NN);                      // N*2
    bf16x8* W1p       = (bf16x8*)(z + (size_t)NN * 2);              // 4096*16B
    int*   cnt2d      = (int*)(W1p + 4096);                         // NCH*NB1
    int*   edge_cnt   = cnt2d + NCH * NB1;                          // NB1
    int*   sorted_src = edge_cnt + NB1;                             // NB1*ARENA
    unsigned int* pairs = (unsigned int*)(sorted_src + (size_t)NB1 * ARENA); // NB1*ARENA

    // K0: zero degree accumulator (custom kernel; rocclr small-fill is ~118us)
    zero_deg_kernel<<<(NN / 4 + 255) / 256, 256, 0, stream>>>((int4*)deg);
    // K1: W1 pack + per-chunk bucket histogram + global degree
    pack_hist_kernel<<<16 + NCH, 256, 0, stream>>>(W1, W1p, dst, cnt2d, deg);
    // K2: arena scatter (redundant chunk-prefix)  ||  gemm tiles [0,GA) -> y, dis
    scatter_gemm_kernel<<<NCH + GA, 256, 0, stream>>>(src, dst, cnt2d, pairs, edge_cnt,
                                                      x, W1p, deg, dis, y);
    // K3: per-bucket CSR sort  ||  gemm tiles [GA,NGEMM)
    sort_gemm_kernel<<<NB1 + GB, 256, 0, stream>>>(pairs, edge_cnt, offsets, cursor,
                                                   sorted_src, x, W1p, deg, dis, y);
    // K4: aggregation layer1 + epilogue + fused GEMM2 -> z = dis*xt2
    agg1_fused_kernel<<<(NN + 3) / 4, 256, 0, stream>>>(offsets, cursor, sorted_src,
                                                        y, dis, b1, W2, z);
    // K5: aggregation layer2 + log_softmax
    agg2_final_kernel<<<(NN + 255) / 256, 256, 0, stream>>>(offsets, cursor, sorted_src,
                                                            dis, z, b2, out);
}

// Round 17
// 173.046 us; speedup vs baseline: 1.3115x; 1.3115x over previous
//
#include <hip/hip_runtime.h>
#include <hip/hip_bf16.h>

#define NN 100000
#define EE 1600000
#define IN_DIM 512
#define HID 64
#define NB1 391          // 256-node buckets: 391*256 = 100096 >= NN
#define NCH 196          // chunks
#define CHUNK 8192       // 196*8192 >= EE
#define NGEMM 1563       // (NN+63)/64
#define ARENA 5120       // per-bucket edge arena (expect ~4092, ~16-sigma margin)
#define GA 800           // gemm tiles in scatter launch
#define GB (NGEMM - GA)  // gemm tiles in sort launch

typedef __attribute__((ext_vector_type(8))) short bf16x8;
typedef __attribute__((ext_vector_type(4))) float f32x4;

static __device__ __forceinline__ short f2bf(float f) {
    __hip_bfloat16 h = __float2bfloat16(f);
    return *reinterpret_cast<short*>(&h);
}
static __device__ __forceinline__ float bf2f(unsigned short u) {
    union { unsigned int i; float f; } c; c.i = ((unsigned int)u) << 16;
    return c.f;
}

// ---- shared device body: MFMA GEMM1 tile (R12 verbatim) ----------------------
__device__ __forceinline__ void do_gemm(int gb, const float* __restrict__ x,
                                        const bf16x8* __restrict__ W1p,
                                        unsigned short* __restrict__ y) {
    const int wave = threadIdx.x >> 6;
    const int lane = threadIdx.x & 63;
    const int r = lane & 15;        // A row within wave tile / B,C col
    const int kg = lane >> 4;       // k-group
    const int row0 = gb * 64 + wave * 16;
    const int rowc = min(row0 + r, NN - 1);
    const float* xr = x + (size_t)rowc * IN_DIM;

    f32x4 acc[4] = {};
#pragma unroll
    for (int ks = 0; ks < 16; ++ks) {
        const int k0 = ks * 32 + kg * 8;
        float4 xa = *(const float4*)(xr + k0);
        float4 xb = *(const float4*)(xr + k0 + 4);
        bf16x8 a;
        a[0] = f2bf(xa.x); a[1] = f2bf(xa.y); a[2] = f2bf(xa.z); a[3] = f2bf(xa.w);
        a[4] = f2bf(xb.x); a[5] = f2bf(xb.y); a[6] = f2bf(xb.z); a[7] = f2bf(xb.w);
        const int bbase = (ks * 4 + kg) * 64;
#pragma unroll
        for (int cb = 0; cb < 4; ++cb) {
            bf16x8 bfr = W1p[bbase + cb * 16 + r];
            acc[cb] = __builtin_amdgcn_mfma_f32_16x16x32_bf16(a, bfr, acc[cb], 0, 0, 0);
        }
    }
    // C/D: col = lane&15 (=r), row = kg*4 + reg
#pragma unroll
    for (int cb = 0; cb < 4; ++cb) {
#pragma unroll
        for (int reg = 0; reg < 4; ++reg) {
            int ro = row0 + kg * 4 + reg;
            if (ro < NN) y[(size_t)ro * HID + cb * 16 + r] =
                (unsigned short)f2bf(acc[cb][reg]);
        }
    }
}

// ---- K1: W1 pack (blocks 0..15) + per-chunk histogram (R12 verbatim) ---------
__global__ __launch_bounds__(256) void pack_hist_kernel(const float* __restrict__ W1,
                                                        bf16x8* __restrict__ W1p,
                                                        const int* __restrict__ dst,
                                                        int* __restrict__ cnt2d) {
    if (blockIdx.x < 16) {
        int t = blockIdx.x * 256 + threadIdx.x;   // 0..4095
        int kstep = t >> 8;
        int kb = (t >> 6) & 3;
        int col = t & 63;
        int kbase = kstep * 32 + kb * 8;
        bf16x8 v;
#pragma unroll
        for (int j = 0; j < 8; ++j) v[j] = f2bf(W1[(size_t)(kbase + j) * HID + col]);
        W1p[t] = v;
    } else {
        __shared__ int h[NB1];
        const int c = blockIdx.x - 16;
        const int t = threadIdx.x;
        for (int i = t; i < NB1; i += 256) h[i] = 0;
        __syncthreads();
        const int base = c * CHUNK;
        for (int i = t; i < CHUNK; i += 256) {
            int e = base + i;
            if (e < EE) atomicAdd(&h[dst[e] >> 8], 1);
        }
        __syncthreads();
        for (int i = t; i < NB1; i += 256) cnt2d[c * NB1 + i] = h[i];
    }
}

// ---- K2: arena scatter w/ redundant chunk-prefix + gemm tiles [0,GA) ---------
__global__ __launch_bounds__(256) void scatter_gemm_kernel(
        const int* __restrict__ src, const int* __restrict__ dst,
        const int* __restrict__ cnt2d, unsigned int* __restrict__ pairs,
        int* __restrict__ edge_cnt,
        const float* __restrict__ x, const bf16x8* __restrict__ W1p,
        unsigned short* __restrict__ y) {
    if (blockIdx.x < NCH) {
        __shared__ int cur[NB1];
        const int c = blockIdx.x;
        const int t = threadIdx.x;
        for (int i = t; i < NB1; i += 256) {
            int run = 0, pp = 0;
            for (int c2 = 0; c2 < NCH; ++c2) {
                int v = cnt2d[c2 * NB1 + i];
                if (c2 == c) pp = run;
                run += v;
            }
            cur[i] = i * ARENA + pp;
            if (c == 0) edge_cnt[i] = run;   // bucket totals (block 0 publishes)
        }
        __syncthreads();
        const int base = c * CHUNK;
        for (int i = t; i < CHUNK; i += 256) {
            int e = base + i;
            if (e < EE) {
                int s = src[e], d = dst[e];
                int bkt = d >> 8;
                int pos = atomicAdd(&cur[bkt], 1);
                if (pos < (bkt + 1) * ARENA)   // safety clamp
                    pairs[pos] = ((unsigned int)s << 8) | (unsigned int)(d & 255);
            }
        }
    } else {
        do_gemm(blockIdx.x - NCH, x, W1p, y);
    }
}

// ---- K3: per-bucket CSR sort + dis (blocks 0..NB1-1) + gemm tiles [GA,NGEMM) -
__global__ __launch_bounds__(256) void sort_gemm_kernel(
        const unsigned int* __restrict__ pairs, const int* __restrict__ edge_cnt,
        int* __restrict__ offsets, int* __restrict__ cursor,
        int* __restrict__ sorted_src, float* __restrict__ dis,
        const float* __restrict__ x, const bf16x8* __restrict__ W1p,
        unsigned short* __restrict__ y) {
    if (blockIdx.x < NB1) {
        __shared__ int sdeg[256];
        __shared__ int sinc[256];
        __shared__ int scur[256];
        const int b = blockIdx.x;
        const int t = threadIdx.x;
        const int n0 = b << 8;
        const int nn = min(256, NN - n0);
        const int e0 = b * ARENA;
        const int e1 = e0 + min(edge_cnt[b], ARENA);

        sdeg[t] = 0;
        __syncthreads();
        for (int e = e0 + t; e < e1; e += 256)
            atomicAdd(&sdeg[pairs[e] & 255u], 1);
        __syncthreads();
        sinc[t] = sdeg[t];
        __syncthreads();
        for (int off = 1; off < 256; off <<= 1) {
            int v = (t >= off) ? sinc[t - off] : 0;
            __syncthreads();
            sinc[t] += v;
            __syncthreads();
        }
        int excl = sinc[t] - sdeg[t];
        scur[t] = excl;
        if (t < nn) {
            offsets[n0 + t] = e0 + excl;
            cursor[n0 + t]  = e0 + excl + sdeg[t];
            dis[n0 + t]     = rsqrtf((float)sdeg[t] + 1.0f);
        }
        __syncthreads();
        for (int e = e0 + t; e < e1; e += 256) {
            unsigned int p = pairs[e];
            int pos = atomicAdd(&scur[p & 255u], 1);
            sorted_src[e0 + pos] = (int)(p >> 8);
        }
    } else {
        do_gemm(GA + (blockIdx.x - NB1), x, W1p, y);
    }
}

// ---- K4: pull aggregation layer1 — ONLY CHANGED KERNEL vs R12 ----------------
// 8 edge groups x bf16x8 gathers (was 4 x ushort4); same per-edge math.
__global__ __launch_bounds__(256) void agg1_fused_kernel(
        const int* __restrict__ offsets, const int* __restrict__ cursor,
        const int* __restrict__ sorted_src, const float* __restrict__ dis,
        const unsigned short* __restrict__ y, const float* __restrict__ b1,
        const float* __restrict__ W2, float* __restrict__ xt2) {
    int node = blockIdx.x * 4 + (threadIdx.x >> 6);
    if (node >= NN) return;
    const int lane = threadIdx.x & 63;
    const int grp = lane >> 3;      // 8 edge groups
    const int fl = lane & 7;        // feature slice: feats fl*8 .. fl*8+7
    const int beg = offsets[node], end = cursor[node];
    const float dd = dis[node];
    float acc[8] = {};

    // self-loop: y[node] * dd (group 0 only; folded in by cross-group reduce)
    if (grp == 0) {
        bf16x8 v = *(const bf16x8*)(y + (size_t)node * HID + fl * 8);
#pragma unroll
        for (int k = 0; k < 8; ++k) acc[k] = bf2f((unsigned short)v[k]) * dd;
    }
    for (int base = beg; base < end; base += 64) {
        int m = min(64, end - base);
        int s = 0;
        float nd = 0.f;
        if (lane < m) {
            s = sorted_src[base + lane];   // coalesced batch load
            nd = dis[s];
        }
#pragma unroll 2
        for (int jj = 0; jj < m; jj += 8) {
            int j = jj + grp;
            if (j < m) {
                int sj = __shfl(s, j);
                float wj = __shfl(nd, j);
                bf16x8 v = *(const bf16x8*)(y + (size_t)sj * HID + fl * 8);
#pragma unroll
                for (int k = 0; k < 8; ++k) acc[k] += bf2f((unsigned short)v[k]) * wj;
            }
        }
    }
    // reduce across the 8 edge groups (lane bits 3,4,5)
#pragma unroll
    for (int k = 0; k < 8; ++k) {
        acc[k] += __shfl_xor(acc[k], 8);
        acc[k] += __shfl_xor(acc[k], 16);
        acc[k] += __shfl_xor(acc[k], 32);
    }
    // h = relu(dd*acc + b1)   [self term becomes dd^2 * y, same as R12]
    float4 b_lo = *(const float4*)(b1 + fl * 8);
    float4 b_hi = *(const float4*)(b1 + fl * 8 + 4);
    float4 w0 = *(const float4*)(W2 + fl * 16);
    float4 w1 = *(const float4*)(W2 + fl * 16 + 4);
    float4 w2 = *(const float4*)(W2 + fl * 16 + 8);
    float4 w3 = *(const float4*)(W2 + fl * 16 + 12);
    float h0 = fmaxf(dd * acc[0] + b_lo.x, 0.f);
    float h1 = fmaxf(dd * acc[1] + b_lo.y, 0.f);
    float h2 = fmaxf(dd * acc[2] + b_lo.z, 0.f);
    float h3 = fmaxf(dd * acc[3] + b_lo.w, 0.f);
    float h4 = fmaxf(dd * acc[4] + b_hi.x, 0.f);
    float h5 = fmaxf(dd * acc[5] + b_hi.y, 0.f);
    float h6 = fmaxf(dd * acc[6] + b_hi.z, 0.f);
    float h7 = fmaxf(dd * acc[7] + b_hi.w, 0.f);
    float a0 = h0 * w0.x + h1 * w0.z + h2 * w1.x + h3 * w1.z
             + h4 * w2.x + h5 * w2.z + h6 * w3.x + h7 * w3.z;
    float a1 = h0 * w0.y + h1 * w0.w + h2 * w1.y + h3 * w1.w
             + h4 * w2.y + h5 * w2.w + h6 * w3.y + h7 * w3.w;
    a0 += __shfl_xor(a0, 1); a0 += __shfl_xor(a0, 2); a0 += __shfl_xor(a0, 4);
    a1 += __shfl_xor(a1, 1); a1 += __shfl_xor(a1, 2); a1 += __shfl_xor(a1, 4);
    if (lane == 0) *(float2*)(xt2 + (size_t)node * 2) = make_float2(a0, a1);
}

// ---- K5: layer2 aggregation + log_softmax (R12 verbatim) ---------------------
__global__ void agg2_final_kernel(const int* __restrict__ offsets, const int* __restrict__ cursor,
                                  const int* __restrict__ sorted_src,
                                  const float* __restrict__ dis,
                                  const float* __restrict__ xt2,
                                  const float* __restrict__ b2,
                                  float* __restrict__ out) {
    int node = blockIdx.x * 256 + threadIdx.x;
    if (node >= NN) return;
    int beg = offsets[node], end = cursor[node];
    float dd = dis[node];
    float d2 = dd * dd;
    float a0 = xt2[(size_t)node * 2 + 0] * d2;
    float a1 = xt2[(size_t)node * 2 + 1] * d2;
    for (int p = beg; p < end; ++p) {
        int s = sorted_src[p];
        float nrm = dis[s] * dd;
        float2 v = *(const float2*)(xt2 + (size_t)s * 2);
        a0 += v.x * nrm;
        a1 += v.y * nrm;
    }
    float v0 = a0 + b2[0], v1 = a1 + b2[1];
    float m = fmaxf(v0, v1);
    float lse = m + logf(expf(v0 - m) + expf(v1 - m));
    out[(size_t)node * 2 + 0] = v0 - lse;
    out[(size_t)node * 2 + 1] = v1 - lse;
}

extern "C" void kernel_launch(void* const* d_in, const int* in_sizes, int n_in,
                              void* d_out, int out_size, void* d_ws, size_t ws_size,
                              hipStream_t stream) {
    const float* x  = (const float*)d_in[0];
    const int* ei   = (const int*)d_in[1];
    const float* W1 = (const float*)d_in[2];
    const float* b1 = (const float*)d_in[3];
    const float* W2 = (const float*)d_in[4];
    const float* b2 = (const float*)d_in[5];
    const int* src = ei;
    const int* dst = ei + EE;
    float* out = (float*)d_out;

    // workspace layout (R12 verbatim)
    unsigned short* y = (unsigned short*)d_ws;                      // N*64 bf16 = 12.8 MB
    float* dis        = (float*)(y + (size_t)NN * HID);             // N
    int*   offsets    = (int*)(dis + NN);                           // N
    int*   cursor     = offsets + NN;                               // N
    float* xt2        = (float*)(cursor + NN);                      // N*2
    bf16x8* W1p       = (bf16x8*)(xt2 + (size_t)NN * 2);            // 4096*16B
    int*   cnt2d      = (int*)(W1p + 4096);                         // NCH*NB1
    int*   edge_cnt   = cnt2d + NCH * NB1;                          // NB1
    int*   sorted_src = edge_cnt + NB1;                             // NB1*ARENA
    unsigned int* pairs = (unsigned int*)(sorted_src + (size_t)NB1 * ARENA); // NB1*ARENA

    // K1: W1 pack + per-chunk bucket histogram
    pack_hist_kernel<<<16 + NCH, 256, 0, stream>>>(W1, W1p, dst, cnt2d);
    // K2: arena scatter (redundant chunk-prefix)  ||  gemm tiles [0,GA)
    scatter_gemm_kernel<<<NCH + GA, 256, 0, stream>>>(src, dst, cnt2d, pairs, edge_cnt,
                                                      x, W1p, y);
    // K3: per-bucket CSR sort + dis  ||  gemm tiles [GA,NGEMM)
    sort_gemm_kernel<<<NB1 + GB, 256, 0, stream>>>(pairs, edge_cnt, offsets, cursor,
                                                   sorted_src, dis, x, W1p, y);
    // K4: aggregation layer1 + epilogue + fused GEMM2
    agg1_fused_kernel<<<(NN + 3) / 4, 256, 0, stream>>>(offsets, cursor, sorted_src,
                                                        dis, y, b1, W2, xt2);
    // K5: aggregation layer2 + log_softmax
    agg2_final_kernel<<<(NN + 255) / 256, 256, 0, stream>>>(offsets, cursor, sorted_src,
                                                            dis, xt2, b2, out);
}

// Round 18
// 169.392 us; speedup vs baseline: 1.3398x; 1.0216x over previous
//
#include <hip/hip_runtime.h>
#include <hip/hip_bf16.h>

#define NN 100000
#define EE 1600000
#define IN_DIM 512
#define HID 64
#define NB1 391          // 256-node buckets: 391*256 = 100096 >= NN
#define NCH 196          // chunks
#define CHUNK 8192       // 196*8192 >= EE
#define NGEMM 1563       // (NN+63)/64
#define ARENA 5120       // per-bucket edge arena (expect ~4092, ~16-sigma margin)
#define GH 400           // gemm tiles in hist launch
#define GA 650           // gemm tiles in scatter launch
#define GB (NGEMM - GH - GA)   // 513, gemm tiles in sort launch

typedef __attribute__((ext_vector_type(8))) short bf16x8;
typedef __attribute__((ext_vector_type(4))) float f32x4;

static __device__ __forceinline__ short f2bf(float f) {
    __hip_bfloat16 h = __float2bfloat16(f);
    return *reinterpret_cast<short*>(&h);
}
static __device__ __forceinline__ float bf2f(unsigned short u) {
    union { unsigned int i; float f; } c; c.i = ((unsigned int)u) << 16;
    return c.f;
}

// ---- K0: W1 pack -> fragment-ordered bf16 (16 blocks) ------------------------
__global__ __launch_bounds__(256) void pack_kernel(const float* __restrict__ W1,
                                                   bf16x8* __restrict__ W1p) {
    int t = blockIdx.x * 256 + threadIdx.x;   // 0..4095
    int kstep = t >> 8;
    int kb = (t >> 6) & 3;
    int col = t & 63;
    int kbase = kstep * 32 + kb * 8;
    bf16x8 v;
#pragma unroll
    for (int j = 0; j < 8; ++j) v[j] = f2bf(W1[(size_t)(kbase + j) * HID + col]);
    W1p[t] = v;
}

// ---- shared device body: MFMA GEMM1 tile (R12 verbatim) ----------------------
__device__ __forceinline__ void do_gemm(int gb, const float* __restrict__ x,
                                        const bf16x8* __restrict__ W1p,
                                        unsigned short* __restrict__ y) {
    const int wave = threadIdx.x >> 6;
    const int lane = threadIdx.x & 63;
    const int r = lane & 15;        // A row within wave tile / B,C col
    const int kg = lane >> 4;       // k-group
    const int row0 = gb * 64 + wave * 16;
    const int rowc = min(row0 + r, NN - 1);
    const float* xr = x + (size_t)rowc * IN_DIM;

    f32x4 acc[4] = {};
#pragma unroll
    for (int ks = 0; ks < 16; ++ks) {
        const int k0 = ks * 32 + kg * 8;
        float4 xa = *(const float4*)(xr + k0);
        float4 xb = *(const float4*)(xr + k0 + 4);
        bf16x8 a;
        a[0] = f2bf(xa.x); a[1] = f2bf(xa.y); a[2] = f2bf(xa.z); a[3] = f2bf(xa.w);
        a[4] = f2bf(xb.x); a[5] = f2bf(xb.y); a[6] = f2bf(xb.z); a[7] = f2bf(xb.w);
        const int bbase = (ks * 4 + kg) * 64;
#pragma unroll
        for (int cb = 0; cb < 4; ++cb) {
            bf16x8 bfr = W1p[bbase + cb * 16 + r];
            acc[cb] = __builtin_amdgcn_mfma_f32_16x16x32_bf16(a, bfr, acc[cb], 0, 0, 0);
        }
    }
    // C/D: col = lane&15 (=r), row = kg*4 + reg
#pragma unroll
    for (int cb = 0; cb < 4; ++cb) {
#pragma unroll
        for (int reg = 0; reg < 4; ++reg) {
            int ro = row0 + kg * 4 + reg;
            if (ro < NN) y[(size_t)ro * HID + cb * 16 + r] =
                (unsigned short)f2bf(acc[cb][reg]);
        }
    }
}

// ---- K1: per-chunk histogram (blocks 0..NCH-1) + gemm tiles [0,GH) -----------
__global__ __launch_bounds__(256) void hist_gemm_kernel(const int* __restrict__ dst,
                                                        int* __restrict__ cnt2d,
                                                        const float* __restrict__ x,
                                                        const bf16x8* __restrict__ W1p,
                                                        unsigned short* __restrict__ y) {
    if (blockIdx.x < NCH) {
        __shared__ int h[NB1];
        const int c = blockIdx.x;
        const int t = threadIdx.x;
        for (int i = t; i < NB1; i += 256) h[i] = 0;
        __syncthreads();
        const int base = c * CHUNK;
        for (int i = t; i < CHUNK; i += 256) {
            int e = base + i;
            if (e < EE) atomicAdd(&h[dst[e] >> 8], 1);
        }
        __syncthreads();
        for (int i = t; i < NB1; i += 256) cnt2d[c * NB1 + i] = h[i];
    } else {
        do_gemm(blockIdx.x - NCH, x, W1p, y);
    }
}

// ---- K2: arena scatter w/ redundant chunk-prefix + gemm tiles [GH,GH+GA) -----
__global__ __launch_bounds__(256) void scatter_gemm_kernel(
        const int* __restrict__ src, const int* __restrict__ dst,
        const int* __restrict__ cnt2d, unsigned int* __restrict__ pairs,
        int* __restrict__ edge_cnt,
        const float* __restrict__ x, const bf16x8* __restrict__ W1p,
        unsigned short* __restrict__ y) {
    if (blockIdx.x < NCH) {
        __shared__ int cur[NB1];
        const int c = blockIdx.x;
        const int t = threadIdx.x;
        for (int i = t; i < NB1; i += 256) {
            int run = 0, pp = 0;
            for (int c2 = 0; c2 < NCH; ++c2) {
                int v = cnt2d[c2 * NB1 + i];
                if (c2 == c) pp = run;
                run += v;
            }
            cur[i] = i * ARENA + pp;
            if (c == 0) edge_cnt[i] = run;   // bucket totals (block 0 publishes)
        }
        __syncthreads();
        const int base = c * CHUNK;
        for (int i = t; i < CHUNK; i += 256) {
            int e = base + i;
            if (e < EE) {
                int s = src[e], d = dst[e];
                int bkt = d >> 8;
                int pos = atomicAdd(&cur[bkt], 1);
                if (pos < (bkt + 1) * ARENA)   // safety clamp
                    pairs[pos] = ((unsigned int)s << 8) | (unsigned int)(d & 255);
            }
        }
    } else {
        do_gemm(GH + (blockIdx.x - NCH), x, W1p, y);
    }
}

// ---- K3: per-bucket CSR sort + dis (blocks 0..NB1-1) + gemm tiles (rest) -----
__global__ __launch_bounds__(256) void sort_gemm_kernel(
        const unsigned int* __restrict__ pairs, const int* __restrict__ edge_cnt,
        int* __restrict__ offsets, int* __restrict__ cursor,
        int* __restrict__ sorted_src, float* __restrict__ dis,
        const float* __restrict__ x, const bf16x8* __restrict__ W1p,
        unsigned short* __restrict__ y) {
    if (blockIdx.x < NB1) {
        __shared__ int sdeg[256];
        __shared__ int sinc[256];
        __shared__ int scur[256];
        const int b = blockIdx.x;
        const int t = threadIdx.x;
        const int n0 = b << 8;
        const int nn = min(256, NN - n0);
        const int e0 = b * ARENA;
        const int e1 = e0 + min(edge_cnt[b], ARENA);

        sdeg[t] = 0;
        __syncthreads();
        for (int e = e0 + t; e < e1; e += 256)
            atomicAdd(&sdeg[pairs[e] & 255u], 1);
        __syncthreads();
        sinc[t] = sdeg[t];
        __syncthreads();
        for (int off = 1; off < 256; off <<= 1) {
            int v = (t >= off) ? sinc[t - off] : 0;
            __syncthreads();
            sinc[t] += v;
            __syncthreads();
        }
        int excl = sinc[t] - sdeg[t];
        scur[t] = excl;
        if (t < nn) {
            offsets[n0 + t] = e0 + excl;
            cursor[n0 + t]  = e0 + excl + sdeg[t];
            dis[n0 + t]     = rsqrtf((float)sdeg[t] + 1.0f);
        }
        __syncthreads();
        for (int e = e0 + t; e < e1; e += 256) {
            unsigned int p = pairs[e];
            int pos = atomicAdd(&scur[p & 255u], 1);
            sorted_src[e0 + pos] = (int)(p >> 8);
        }
    } else {
        do_gemm(GH + GA + (blockIdx.x - NB1), x, W1p, y);
    }
}

// ---- K4: pull aggregation layer1 (R12 verbatim: 4 groups x ushort4) ----------
__global__ __launch_bounds__(256) void agg1_fused_kernel(
        const int* __restrict__ offsets, const int* __restrict__ cursor,
        const int* __restrict__ sorted_src, const float* __restrict__ dis,
        const unsigned short* __restrict__ y, const float* __restrict__ b1,
        const float* __restrict__ W2, float* __restrict__ xt2) {
    int node = blockIdx.x * 4 + (threadIdx.x >> 6);
    if (node >= NN) return;
    const int lane = threadIdx.x & 63;
    const int grp = lane >> 4;
    const int fl = lane & 15;
    const int beg = offsets[node], end = cursor[node];
    const float dd = dis[node];
    float acc0 = 0.f, acc1 = 0.f, acc2 = 0.f, acc3 = 0.f;

    for (int base = beg; base < end; base += 64) {
        int m = min(64, end - base);
        int s = 0;
        float nd = 0.f;
        if (lane < m) {
            s = sorted_src[base + lane];   // coalesced batch load
            nd = dis[s];
        }
#pragma unroll 4
        for (int jj = 0; jj < m; jj += 4) {
            int j = jj + grp;
            int sj = __shfl(s, j);
            float nj = __shfl(nd, j);
            float w = (j < m) ? nj : 0.f;
            ushort4 v = *(const ushort4*)(y + (size_t)sj * HID + fl * 4);
            acc0 += bf2f(v.x) * w;
            acc1 += bf2f(v.y) * w;
            acc2 += bf2f(v.z) * w;
            acc3 += bf2f(v.w) * w;
        }
    }
    // sum the 4 edge groups (lanes with equal fl)
    acc0 += __shfl_xor(acc0, 16); acc0 += __shfl_xor(acc0, 32);
    acc1 += __shfl_xor(acc1, 16); acc1 += __shfl_xor(acc1, 32);
    acc2 += __shfl_xor(acc2, 16); acc2 += __shfl_xor(acc2, 32);
    acc3 += __shfl_xor(acc3, 16); acc3 += __shfl_xor(acc3, 32);

    // self-loop + bias + relu
    ushort4 xs = *(const ushort4*)(y + (size_t)node * HID + fl * 4);
    float4 bb = *(const float4*)(b1 + fl * 4);
    float d2 = dd * dd;
    float h0 = fmaxf(acc0 * dd + bf2f(xs.x) * d2 + bb.x, 0.f);
    float h1 = fmaxf(acc1 * dd + bf2f(xs.y) * d2 + bb.y, 0.f);
    float h2 = fmaxf(acc2 * dd + bf2f(xs.z) * d2 + bb.z, 0.f);
    float h3 = fmaxf(acc3 * dd + bf2f(xs.w) * d2 + bb.w, 0.f);

    // fused GEMM2
    float4 w01 = *(const float4*)(W2 + fl * 8);
    float4 w23 = *(const float4*)(W2 + fl * 8 + 4);
    float a0 = h0 * w01.x + h1 * w01.z + h2 * w23.x + h3 * w23.z;
    float a1 = h0 * w01.y + h1 * w01.w + h2 * w23.y + h3 * w23.w;
    a0 += __shfl_xor(a0, 1); a0 += __shfl_xor(a0, 2);
    a0 += __shfl_xor(a0, 4); a0 += __shfl_xor(a0, 8);
    a1 += __shfl_xor(a1, 1); a1 += __shfl_xor(a1, 2);
    a1 += __shfl_xor(a1, 4); a1 += __shfl_xor(a1, 8);
    if (lane == 0) *(float2*)(xt2 + (size_t)node * 2) = make_float2(a0, a1);
}

// ---- K5: layer2 aggregation + log_softmax (R12 verbatim) ---------------------
__global__ void agg2_final_kernel(const int* __restrict__ offsets, const int* __restrict__ cursor,
                                  const int* __restrict__ sorted_src,
                                  const float* __restrict__ dis,
                                  const float* __restrict__ xt2,
                                  const float* __restrict__ b2,
                                  float* __restrict__ out) {
    int node = blockIdx.x * 256 + threadIdx.x;
    if (node >= NN) return;
    int beg = offsets[node], end = cursor[node];
    float dd = dis[node];
    float d2 = dd * dd;
    float a0 = xt2[(size_t)node * 2 + 0] * d2;
    float a1 = xt2[(size_t)node * 2 + 1] * d2;
    for (int p = beg; p < end; ++p) {
        int s = sorted_src[p];
        float nrm = dis[s] * dd;
        float2 v = *(const float2*)(xt2 + (size_t)s * 2);
        a0 += v.x * nrm;
        a1 += v.y * nrm;
    }
    float v0 = a0 + b2[0], v1 = a1 + b2[1];
    float m = fmaxf(v0, v1);
    float lse = m + logf(expf(v0 - m) + expf(v1 - m));
    out[(size_t)node * 2 + 0] = v0 - lse;
    out[(size_t)node * 2 + 1] = v1 - lse;
}

extern "C" void kernel_launch(void* const* d_in, const int* in_sizes, int n_in,
                              void* d_out, int out_size, void* d_ws, size_t ws_size,
                              hipStream_t stream) {
    const float* x  = (const float*)d_in[0];
    const int* ei   = (const int*)d_in[1];
    const float* W1 = (const float*)d_in[2];
    const float* b1 = (const float*)d_in[3];
    const float* W2 = (const float*)d_in[4];
    const float* b2 = (const float*)d_in[5];
    const int* src = ei;
    const int* dst = ei + EE;
    float* out = (float*)d_out;

    // workspace layout (R12 verbatim)
    unsigned short* y = (unsigned short*)d_ws;                      // N*64 bf16 = 12.8 MB
    float* dis        = (float*)(y + (size_t)NN * HID);             // N
    int*   offsets    = (int*)(dis + NN);                           // N
    int*   cursor     = offsets + NN;                               // N
    float* xt2        = (float*)(cursor + NN);                      // N*2
    bf16x8* W1p       = (bf16x8*)(xt2 + (size_t)NN * 2);            // 4096*16B
    int*   cnt2d      = (int*)(W1p + 4096);                         // NCH*NB1
    int*   edge_cnt   = cnt2d + NCH * NB1;                          // NB1
    int*   sorted_src = edge_cnt + NB1;                             // NB1*ARENA
    unsigned int* pairs = (unsigned int*)(sorted_src + (size_t)NB1 * ARENA); // NB1*ARENA

    // K0: W1 pack (tiny; lets gemm overlap the histogram too)
    pack_kernel<<<16, 256, 0, stream>>>(W1, W1p);
    // K1: per-chunk bucket histogram  ||  gemm tiles [0,GH)
    hist_gemm_kernel<<<NCH + GH, 256, 0, stream>>>(dst, cnt2d, x, W1p, y);
    // K2: arena scatter (redundant chunk-prefix)  ||  gemm tiles [GH,GH+GA)
    scatter_gemm_kernel<<<NCH + GA, 256, 0, stream>>>(src, dst, cnt2d, pairs, edge_cnt,
                                                      x, W1p, y);
    // K3: per-bucket CSR sort + dis  ||  gemm tiles [GH+GA,NGEMM)
    sort_gemm_kernel<<<NB1 + GB, 256, 0, stream>>>(pairs, edge_cnt, offsets, cursor,
                                                   sorted_src, dis, x, W1p, y);
    // K4: aggregation layer1 + epilogue + fused GEMM2
    agg1_fused_kernel<<<(NN + 3) / 4, 256, 0, stream>>>(offsets, cursor, sorted_src,
                                                        dis, y, b1, W2, xt2);
    // K5: aggregation layer2 + log_softmax
    agg2_final_kernel<<<(NN + 255) / 256, 256, 0, stream>>>(offsets, cursor, sorted_src,
                                                            dis, xt2, b2, out);
}

// Round 19
// 165.087 us; speedup vs baseline: 1.3747x; 1.0261x over previous
//
#include <hip/hip_runtime.h>
#include <hip/hip_bf16.h>

#define NN 100000
#define EE 1600000
#define IN_DIM 512
#define HID 64
#define NB1 391          // 256-node buckets: 391*256 = 100096 >= NN
#define NCH 196          // chunks
#define CHUNK 8192       // 196*8192 >= EE
#define NGEMM 1563       // (NN+63)/64
#define ARENA 5120       // per-bucket edge arena (expect ~4092, ~16-sigma margin)
#define GA 800           // gemm tiles in scatter launch
#define GB (NGEMM - GA)  // gemm tiles in sort launch

typedef __attribute__((ext_vector_type(8))) short bf16x8;
typedef __attribute__((ext_vector_type(4))) float f32x4;

static __device__ __forceinline__ short f2bf(float f) {
    __hip_bfloat16 h = __float2bfloat16(f);
    return *reinterpret_cast<short*>(&h);
}
static __device__ __forceinline__ float bf2f(unsigned short u) {
    union { unsigned int i; float f; } c; c.i = ((unsigned int)u) << 16;
    return c.f;
}

// ---- shared device body: MFMA GEMM1 tile ----------------------
__device__ __forceinline__ void do_gemm(int gb, const float* __restrict__ x,
                                        const bf16x8* __restrict__ W1p,
                                        unsigned short* __restrict__ y) {
    const int wave = threadIdx.x >> 6;
    const int lane = threadIdx.x & 63;
    const int r = lane & 15;        // A row within wave tile / B,C col
    const int kg = lane >> 4;       // k-group
    const int row0 = gb * 64 + wave * 16;
    const int rowc = min(row0 + r, NN - 1);
    const float* xr = x + (size_t)rowc * IN_DIM;

    f32x4 acc[4] = {};
#pragma unroll
    for (int ks = 0; ks < 16; ++ks) {
        const int k0 = ks * 32 + kg * 8;
        float4 xa = *(const float4*)(xr + k0);
        float4 xb = *(const float4*)(xr + k0 + 4);
        bf16x8 a;
        a[0] = f2bf(xa.x); a[1] = f2bf(xa.y); a[2] = f2bf(xa.z); a[3] = f2bf(xa.w);
        a[4] = f2bf(xb.x); a[5] = f2bf(xb.y); a[6] = f2bf(xb.z); a[7] = f2bf(xb.w);
        const int bbase = (ks * 4 + kg) * 64;
#pragma unroll
        for (int cb = 0; cb < 4; ++cb) {
            bf16x8 bfr = W1p[bbase + cb * 16 + r];
            acc[cb] = __builtin_amdgcn_mfma_f32_16x16x32_bf16(a, bfr, acc[cb], 0, 0, 0);
        }
    }
    // C/D: col = lane&15 (=r), row = kg*4 + reg
#pragma unroll
    for (int cb = 0; cb < 4; ++cb) {
#pragma unroll
        for (int reg = 0; reg < 4; ++reg) {
            int ro = row0 + kg * 4 + reg;
            if (ro < NN) y[(size_t)ro * HID + cb * 16 + r] =
                (unsigned short)f2bf(acc[cb][reg]);
        }
    }
}

// ---- K1: W1 pack (blocks 0..15) + per-chunk histogram ------------------------
__global__ __launch_bounds__(256) void pack_hist_kernel(const float* __restrict__ W1,
                                                        bf16x8* __restrict__ W1p,
                                                        const int* __restrict__ dst,
                                                        int* __restrict__ cnt2d) {
    if (blockIdx.x < 16) {
        int t = blockIdx.x * 256 + threadIdx.x;   // 0..4095
        int kstep = t >> 8;
        int kb = (t >> 6) & 3;
        int col = t & 63;
        int kbase = kstep * 32 + kb * 8;
        bf16x8 v;
#pragma unroll
        for (int j = 0; j < 8; ++j) v[j] = f2bf(W1[(size_t)(kbase + j) * HID + col]);
        W1p[t] = v;
    } else {
        __shared__ int h[NB1];
        const int c = blockIdx.x - 16;
        const int t = threadIdx.x;
        for (int i = t; i < NB1; i += 256) h[i] = 0;
        __syncthreads();
        const int base = c * CHUNK;
        for (int i = t; i < CHUNK; i += 256) {
            int e = base + i;
            if (e < EE) atomicAdd(&h[dst[e] >> 8], 1);
        }
        __syncthreads();
        for (int i = t; i < NB1; i += 256) cnt2d[c * NB1 + i] = h[i];
    }
}

// ---- K2: arena scatter w/ redundant chunk-prefix + gemm tiles [0,GA) ---------
__global__ __launch_bounds__(256) void scatter_gemm_kernel(
        const int* __restrict__ src, const int* __restrict__ dst,
        const int* __restrict__ cnt2d, unsigned int* __restrict__ pairs,
        int* __restrict__ edge_cnt,
        const float* __restrict__ x, const bf16x8* __restrict__ W1p,
        unsigned short* __restrict__ y) {
    if (blockIdx.x < NCH) {
        __shared__ int cur[NB1];
        const int c = blockIdx.x;
        const int t = threadIdx.x;
        for (int i = t; i < NB1; i += 256) {
            int run = 0, pp = 0;
            for (int c2 = 0; c2 < NCH; ++c2) {
                int v = cnt2d[c2 * NB1 + i];
                if (c2 == c) pp = run;
                run += v;
            }
            cur[i] = i * ARENA + pp;
            if (c == 0) edge_cnt[i] = run;   // bucket totals (block 0 publishes)
        }
        __syncthreads();
        const int base = c * CHUNK;
        for (int i = t; i < CHUNK; i += 256) {
            int e = base + i;
            if (e < EE) {
                int s = src[e], d = dst[e];
                int bkt = d >> 8;
                int pos = atomicAdd(&cur[bkt], 1);
                if (pos < (bkt + 1) * ARENA)   // safety clamp
                    pairs[pos] = ((unsigned int)s << 8) | (unsigned int)(d & 255);
            }
        }
    } else {
        do_gemm(blockIdx.x - NCH, x, W1p, y);
    }
}

// ---- K3: per-bucket CSR sort + dis (blocks 0..NB1-1) + gemm tiles [GA,NGEMM) -
__global__ __launch_bounds__(256) void sort_gemm_kernel(
        const unsigned int* __restrict__ pairs, const int* __restrict__ edge_cnt,
        int* __restrict__ offsets, int* __restrict__ cursor,
        int* __restrict__ sorted_src, float* __restrict__ dis,
        const float* __restrict__ x, const bf16x8* __restrict__ W1p,
        unsigned short* __restrict__ y) {
    if (blockIdx.x < NB1) {
        __shared__ int sdeg[256];
        __shared__ int sinc[256];
        __shared__ int scur[256];
        const int b = blockIdx.x;
        const int t = threadIdx.x;
        const int n0 = b << 8;
        const int nn = min(256, NN - n0);
        const int e0 = b * ARENA;
        const int e1 = e0 + min(edge_cnt[b], ARENA);

        sdeg[t] = 0;
        __syncthreads();
        for (int e = e0 + t; e < e1; e += 256)
            atomicAdd(&sdeg[pairs[e] & 255u], 1);
        __syncthreads();
        sinc[t] = sdeg[t];
        __syncthreads();
        for (int off = 1; off < 256; off <<= 1) {
            int v = (t >= off) ? sinc[t - off] : 0;
            __syncthreads();
            sinc[t] += v;
            __syncthreads();
        }
        int excl = sinc[t] - sdeg[t];
        scur[t] = excl;
        if (t < nn) {
            offsets[n0 + t] = e0 + excl;
            cursor[n0 + t]  = e0 + excl + sdeg[t];
            dis[n0 + t]     = rsqrtf((float)sdeg[t] + 1.0f);
        }
        __syncthreads();
        for (int e = e0 + t; e < e1; e += 256) {
            unsigned int p = pairs[e];
            int pos = atomicAdd(&scur[p & 255u], 1);
            sorted_src[e0 + pos] = (int)(p >> 8);
        }
    } else {
        do_gemm(GA + (blockIdx.x - NB1), x, W1p, y);
    }
}

// ---- K4: pull aggregation layer1 (wave/node, 4 edge groups) + fused GEMM2 ----
__global__ __launch_bounds__(256) void agg1_fused_kernel(
        const int* __restrict__ offsets, const int* __restrict__ cursor,
        const int* __restrict__ sorted_src, const float* __restrict__ dis,
        const unsigned short* __restrict__ y, const float* __restrict__ b1,
        const float* __restrict__ W2, float* __restrict__ xt2) {
    int node = blockIdx.x * 4 + (threadIdx.x >> 6);
    if (node >= NN) return;
    const int lane = threadIdx.x & 63;
    const int grp = lane >> 4;
    const int fl = lane & 15;
    const int beg = offsets[node], end = cursor[node];
    const float dd = dis[node];
    float acc0 = 0.f, acc1 = 0.f, acc2 = 0.f, acc3 = 0.f;

    for (int base = beg; base < end; base += 64) {
        int m = min(64, end - base);
        int s = 0;
        float nd = 0.f;
        if (lane < m) {
            s = sorted_src[base + lane];   // coalesced batch load
            nd = dis[s];
        }
#pragma unroll 4
        for (int jj = 0; jj < m; jj += 4) {
            int j = jj + grp;
            int sj = __shfl(s, j);
            float nj = __shfl(nd, j);
            float w = (j < m) ? nj : 0.f;
            ushort4 v = *(const ushort4*)(y + (size_t)sj * HID + fl * 4);
            acc0 += bf2f(v.x) * w;
            acc1 += bf2f(v.y) * w;
            acc2 += bf2f(v.z) * w;
            acc3 += bf2f(v.w) * w;
        }
    }
    // sum the 4 edge groups (lanes with equal fl)
    acc0 += __shfl_xor(acc0, 16); acc0 += __shfl_xor(acc0, 32);
    acc1 += __shfl_xor(acc1, 16); acc1 += __shfl_xor(acc1, 32);
    acc2 += __shfl_xor(acc2, 16); acc2 += __shfl_xor(acc2, 32);
    acc3 += __shfl_xor(acc3, 16); acc3 += __shfl_xor(acc3, 32);

    // self-loop + bias + relu
    ushort4 xs = *(const ushort4*)(y + (size_t)node * HID + fl * 4);
    float4 bb = *(const float4*)(b1 + fl * 4);
    float d2 = dd * dd;
    float h0 = fmaxf(acc0 * dd + bf2f(xs.x) * d2 + bb.x, 0.f);
    float h1 = fmaxf(acc1 * dd + bf2f(xs.y) * d2 + bb.y, 0.f);
    float h2 = fmaxf(acc2 * dd + bf2f(xs.z) * d2 + bb.z, 0.f);
    float h3 = fmaxf(acc3 * dd + bf2f(xs.w) * d2 + bb.w, 0.f);

    // fused GEMM2
    float4 w01 = *(const float4*)(W2 + fl * 8);
    float4 w23 = *(const float4*)(W2 + fl * 8 + 4);
    float a0 = h0 * w01.x + h1 * w01.z + h2 * w23.x + h3 * w23.z;
    float a1 = h0 * w01.y + h1 * w01.w + h2 * w23.y + h3 * w23.w;
    a0 += __shfl_xor(a0, 1); a0 += __shfl_xor(a0, 2);
    a0 += __shfl_xor(a0, 4); a0 += __shfl_xor(a0, 8);
    a1 += __shfl_xor(a1, 1); a1 += __shfl_xor(a1, 2);
    a1 += __shfl_xor(a1, 4); a1 += __shfl_xor(a1, 8);
    if (lane == 0) *(float2*)(xt2 + (size_t)node * 2) = make_float2(a0, a1);
}

// ---- K5: layer2 aggregation + log_softmax ------------------------------------
__global__ void agg2_final_kernel(const int* __restrict__ offsets, const int* __restrict__ cursor,
                                  const int* __restrict__ sorted_src,
                                  const float* __restrict__ dis,
                                  const float* __restrict__ xt2,
                                  const float* __restrict__ b2,
                                  float* __restrict__ out) {
    int node = blockIdx.x * 256 + threadIdx.x;
    if (node >= NN) return;
    int beg = offsets[node], end = cursor[node];
    float dd = dis[node];
    float d2 = dd * dd;
    float a0 = xt2[(size_t)node * 2 + 0] * d2;
    float a1 = xt2[(size_t)node * 2 + 1] * d2;
    for (int p = beg; p < end; ++p) {
        int s = sorted_src[p];
        float nrm = dis[s] * dd;
        float2 v = *(const float2*)(xt2 + (size_t)s * 2);
        a0 += v.x * nrm;
        a1 += v.y * nrm;
    }
    float v0 = a0 + b2[0], v1 = a1 + b2[1];
    float m = fmaxf(v0, v1);
    float lse = m + logf(expf(v0 - m) + expf(v1 - m));
    out[(size_t)node * 2 + 0] = v0 - lse;
    out[(size_t)node * 2 + 1] = v1 - lse;
}

extern "C" void kernel_launch(void* const* d_in, const int* in_sizes, int n_in,
                              void* d_out, int out_size, void* d_ws, size_t ws_size,
                              hipStream_t stream) {
    const float* x  = (const float*)d_in[0];
    const int* ei   = (const int*)d_in[1];
    const float* W1 = (const float*)d_in[2];
    const float* b1 = (const float*)d_in[3];
    const float* W2 = (const float*)d_in[4];
    const float* b2 = (const float*)d_in[5];
    const int* src = ei;
    const int* dst = ei + EE;
    float* out = (float*)d_out;

    // workspace layout
    unsigned short* y = (unsigned short*)d_ws;                      // N*64 bf16 = 12.8 MB
    float* dis        = (float*)(y + (size_t)NN * HID);             // N
    int*   offsets    = (int*)(dis + NN);                           // N
    int*   cursor     = offsets + NN;                               // N
    float* xt2        = (float*)(cursor + NN);                      // N*2
    bf16x8* W1p       = (bf16x8*)(xt2 + (size_t)NN * 2);            // 4096*16B
    int*   cnt2d      = (int*)(W1p + 4096);                         // NCH*NB1
    int*   edge_cnt   = cnt2d + NCH * NB1;                          // NB1
    int*   sorted_src = edge_cnt + NB1;                             // NB1*ARENA
    unsigned int* pairs = (unsigned int*)(sorted_src + (size_t)NB1 * ARENA); // NB1*ARENA

    // K1: W1 pack + per-chunk bucket histogram
    pack_hist_kernel<<<16 + NCH, 256, 0, stream>>>(W1, W1p, dst, cnt2d);
    // K2: arena scatter (redundant chunk-prefix)  ||  gemm tiles [0,GA)
    scatter_gemm_kernel<<<NCH + GA, 256, 0, stream>>>(src, dst, cnt2d, pairs, edge_cnt,
                                                      x, W1p, y);
    // K3: per-bucket CSR sort + dis  ||  gemm tiles [GA,NGEMM)
    sort_gemm_kernel<<<NB1 + GB, 256, 0, stream>>>(pairs, edge_cnt, offsets, cursor,
                                                   sorted_src, dis, x, W1p, y);
    // K4: aggregation layer1 + epilogue + fused GEMM2
    agg1_fused_kernel<<<(NN + 3) / 4, 256, 0, stream>>>(offsets, cursor, sorted_src,
                                                        dis, y, b1, W2, xt2);
    // K5: aggregation layer2 + log_softmax
    agg2_final_kernel<<<(NN + 255) / 256, 256, 0, stream>>>(offsets, cursor, sorted_src,
                                                            dis, xt2, b2, out);
}